// Round 1
// baseline (20613.307 us; speedup 1.0000x reference)
//
#include <hip/hip_runtime.h>
#include <hip/hip_bf16.h>

#define HDIM 128
#define LN_EPS 1e-5f

__device__ __forceinline__ float sigmoidf_(float x) {
    return 1.0f / (1.0f + __expf(-x));
}

// ---------------- zero workspace (N only known on device) ----------------
__global__ void zero_ws_kernel(float* __restrict__ ws, const int* __restrict__ n_nodes_p) {
    const long long N = *n_nodes_p;
    const long long total = N * 257;  // aggL (N*128) + aggR (N*128) + cnt (N)
    const long long stride = (long long)gridDim.x * blockDim.x;
    for (long long i = (long long)blockIdx.x * blockDim.x + threadIdx.x; i < total; i += stride)
        ws[i] = 0.0f;
}

// ---------------- LN + dual gate GEMM + sigmoid + atomic scatter ----------------
// block = 256 threads, 64 edges per block
__global__ __launch_bounds__(256) void gates_kernel(
    const float* __restrict__ y, const int* __restrict__ dst,
    const float* __restrict__ ln_g, const float* __restrict__ ln_b,
    const float* __restrict__ Wl, const float* __restrict__ bl,
    const float* __restrict__ Wr, const float* __restrict__ br,
    float* __restrict__ ws, const int* __restrict__ n_nodes_p, int E)
{
    __shared__ float sYn[64][129];   // +1 pad: GEMM reads are 2-addr broadcasts, conflict-free
    __shared__ float sW[32][128];    // 32-row chunk of W, row-aligned b128 reads

    const int N = *n_nodes_p;
    float* aggL = ws;
    float* aggR = ws + (size_t)N * 128;
    float* cnt  = ws + (size_t)N * 256;

    const int t  = threadIdx.x;
    const int e0 = blockIdx.x * 64;

    // edge counts (once per edge)
    if (t < 64) {
        const int e = e0 + t;
        if (e < E) atomicAdd(&cnt[dst[e]], 1.0f);
    }

    // --- LayerNorm: 4 threads per row, cols 4*sub + 16*j (+m) ---
    {
        const int r = t >> 2, sub = t & 3;
        const int e = e0 + r;
        const float* yr = y + (size_t)(e < E ? e : (E - 1)) * HDIM;
        float v[32];
        #pragma unroll
        for (int j = 0; j < 8; ++j) {
            const float4 q = *reinterpret_cast<const float4*>(yr + 4 * sub + 16 * j);
            v[4*j+0] = q.x; v[4*j+1] = q.y; v[4*j+2] = q.z; v[4*j+3] = q.w;
        }
        float s = 0.f, sq = 0.f;
        #pragma unroll
        for (int j = 0; j < 32; ++j) { s += v[j]; sq += v[j] * v[j]; }
        s  += __shfl_xor(s, 1);  s  += __shfl_xor(s, 2);
        sq += __shfl_xor(sq, 1); sq += __shfl_xor(sq, 2);
        const float mu   = s * (1.0f / 128.0f);
        const float var  = sq * (1.0f / 128.0f) - mu * mu;
        const float rstd = rsqrtf(var + LN_EPS);
        #pragma unroll
        for (int j = 0; j < 8; ++j) {
            #pragma unroll
            for (int m = 0; m < 4; ++m) {
                const int c = 4 * sub + 16 * j + m;
                sYn[r][c] = (v[4*j+m] - mu) * rstd * ln_g[c] + ln_b[c];
            }
        }
    }

    const int cq = t & 31;   // output col quad (4 cols)
    const int er = t >> 5;   // edge group 0..7, edges er*8 .. er*8+7

    const float* Wg[2] = { Wl, Wr };
    const float* bg[2] = { bl, br };
    float*       ag[2] = { aggL, aggR };

    for (int g = 0; g < 2; ++g) {
        float4 acc[8];
        #pragma unroll
        for (int i = 0; i < 8; ++i) acc[i] = make_float4(0.f, 0.f, 0.f, 0.f);

        for (int ch = 0; ch < 4; ++ch) {
            __syncthreads();
            #pragma unroll
            for (int i = 0; i < 4; ++i) {
                const int idx  = i * 256 + t;
                const int row  = idx >> 5;
                const int col4 = (idx & 31) << 2;
                *reinterpret_cast<float4*>(&sW[row][col4]) =
                    *reinterpret_cast<const float4*>(Wg[g] + (size_t)(ch * 32 + row) * HDIM + col4);
            }
            __syncthreads();
            for (int kk = 0; kk < 32; ++kk) {
                const float4 w = *reinterpret_cast<const float4*>(&sW[kk][cq << 2]);
                #pragma unroll
                for (int i = 0; i < 8; ++i) {
                    const float a = sYn[er * 8 + i][ch * 32 + kk];
                    acc[i].x = fmaf(a, w.x, acc[i].x);
                    acc[i].y = fmaf(a, w.y, acc[i].y);
                    acc[i].z = fmaf(a, w.z, acc[i].z);
                    acc[i].w = fmaf(a, w.w, acc[i].w);
                }
            }
        }

        const float4 bb = *reinterpret_cast<const float4*>(bg[g] + (cq << 2));
        #pragma unroll
        for (int i = 0; i < 8; ++i) {
            const int e = e0 + er * 8 + i;
            if (e < E) {
                const int node = dst[e];
                float* dest = ag[g] + (size_t)node * HDIM + (cq << 2);
                atomicAdd(dest + 0, sigmoidf_(acc[i].x + bb.x));
                atomicAdd(dest + 1, sigmoidf_(acc[i].y + bb.y));
                atomicAdd(dest + 2, sigmoidf_(acc[i].z + bb.z));
                atomicAdd(dest + 3, sigmoidf_(acc[i].w + bb.w));
            }
        }
    }
}

// ---------------- rdenom = 1/max(cnt,1), in place ----------------
__global__ void rdenom_kernel(float* __restrict__ ws, const int* __restrict__ n_nodes_p) {
    const int N = *n_nodes_p;
    float* cnt = ws + (size_t)N * 256;
    const int stride = gridDim.x * blockDim.x;
    for (int i = blockIdx.x * blockDim.x + threadIdx.x; i < N; i += stride)
        cnt[i] = 1.0f / fmaxf(cnt[i], 1.0f);
}

// ---------------- gather + LN(256) + MLP GEMM + ELU + dot ----------------
// block = 256 threads, 32 edges per block
__global__ __launch_bounds__(256) void mlp_kernel(
    const int* __restrict__ src, const int* __restrict__ dst,
    const float* __restrict__ ln2_g, const float* __restrict__ ln2_b,
    const float* __restrict__ W1, const float* __restrict__ b1,
    const float* __restrict__ W2, const float* __restrict__ b2,
    const float* __restrict__ ws, const int* __restrict__ n_nodes_p,
    float* __restrict__ out, int E)
{
    __shared__ float sH[32][264];    // pad 264: 8*e stride, e = er + 8i -> 2-way (free)
    __shared__ float sW[32][128];

    const int N = *n_nodes_p;
    const float* aggL = ws;
    const float* aggR = ws + (size_t)N * 128;
    const float* rd   = ws + (size_t)N * 256;

    const int t  = threadIdx.x;
    const int e0 = blockIdx.x * 32;

    // --- gather h = [aggL[src]*rd[src] | aggR[dst]*rd[dst]] into LDS ---
    {
        const int hr   = t >> 2;         // 0..63 half-rows
        const int sub  = t & 3;
        const int er_  = hr & 31;
        const int half = hr >> 5;
        const int e    = e0 + er_;
        if (e < E) {
            const int node = (half == 0) ? src[e] : dst[e];
            const float* srow = ((half == 0) ? aggL : aggR) + (size_t)node * HDIM;
            const float scale = rd[node];
            #pragma unroll
            for (int j = 0; j < 8; ++j) {
                float4 q = *reinterpret_cast<const float4*>(srow + 4 * sub + 16 * j);
                q.x *= scale; q.y *= scale; q.z *= scale; q.w *= scale;
                *reinterpret_cast<float4*>(&sH[er_][half * HDIM + 4 * sub + 16 * j]) = q;
            }
        } else {
            #pragma unroll
            for (int j = 0; j < 8; ++j)
                *reinterpret_cast<float4*>(&sH[er_][half * HDIM + 4 * sub + 16 * j]) =
                    make_float4(0.f, 0.f, 0.f, 0.f);
        }
    }
    __syncthreads();

    // --- LayerNorm over 256: 8 threads per edge, cols oct + 8j (2-way banks, free) ---
    {
        const int r   = t >> 3;          // 0..31
        const int oct = t & 7;
        float vv[32];
        float s = 0.f, sq = 0.f;
        #pragma unroll
        for (int j = 0; j < 32; ++j) {
            const float x = sH[r][oct + 8 * j];
            vv[j] = x; s += x; sq += x * x;
        }
        s  += __shfl_xor(s, 1);  s  += __shfl_xor(s, 2);  s  += __shfl_xor(s, 4);
        sq += __shfl_xor(sq, 1); sq += __shfl_xor(sq, 2); sq += __shfl_xor(sq, 4);
        const float mu   = s * (1.0f / 256.0f);
        const float var  = sq * (1.0f / 256.0f) - mu * mu;
        const float rstd = rsqrtf(var + LN_EPS);
        #pragma unroll
        for (int j = 0; j < 32; ++j) {
            const int c = oct + 8 * j;
            sH[r][c] = (vv[j] - mu) * rstd * ln2_g[c] + ln2_b[c];
        }
    }
    __syncthreads();

    // --- GEMM [32,256]@[256,128] ---
    const int cq = t & 31;
    const int er = t >> 5;

    float4 acc[4];
    #pragma unroll
    for (int i = 0; i < 4; ++i) acc[i] = make_float4(0.f, 0.f, 0.f, 0.f);

    for (int ch = 0; ch < 8; ++ch) {
        __syncthreads();
        #pragma unroll
        for (int i = 0; i < 4; ++i) {
            const int idx  = i * 256 + t;
            const int row  = idx >> 5;
            const int col4 = (idx & 31) << 2;
            *reinterpret_cast<float4*>(&sW[row][col4]) =
                *reinterpret_cast<const float4*>(W1 + (size_t)(ch * 32 + row) * HDIM + col4);
        }
        __syncthreads();
        for (int kk = 0; kk < 32; ++kk) {
            const float4 w = *reinterpret_cast<const float4*>(&sW[kk][cq << 2]);
            #pragma unroll
            for (int i = 0; i < 4; ++i) {
                const float a = sH[er + 8 * i][ch * 32 + kk];
                acc[i].x = fmaf(a, w.x, acc[i].x);
                acc[i].y = fmaf(a, w.y, acc[i].y);
                acc[i].z = fmaf(a, w.z, acc[i].z);
                acc[i].w = fmaf(a, w.w, acc[i].w);
            }
        }
    }

    // --- bias + ELU + dot(W2) + reduce across 32 col-lanes ---
    const float4 b1q = *reinterpret_cast<const float4*>(b1 + (cq << 2));
    const float4 w2q = *reinterpret_cast<const float4*>(W2 + (cq << 2));
    const float bias2 = b2[0];
    #pragma unroll
    for (int i = 0; i < 4; ++i) {
        float4 u = acc[i];
        u.x += b1q.x; u.y += b1q.y; u.z += b1q.z; u.w += b1q.w;
        u.x = u.x > 0.f ? u.x : __expf(u.x) - 1.f;
        u.y = u.y > 0.f ? u.y : __expf(u.y) - 1.f;
        u.z = u.z > 0.f ? u.z : __expf(u.z) - 1.f;
        u.w = u.w > 0.f ? u.w : __expf(u.w) - 1.f;
        float p = u.x * w2q.x + u.y * w2q.y + u.z * w2q.z + u.w * w2q.w;
        #pragma unroll
        for (int m = 16; m >= 1; m >>= 1) p += __shfl_xor(p, m);
        if (cq == 0) {
            const int e = e0 + er + 8 * i;
            if (e < E) out[e] = p + bias2;
        }
    }
}

extern "C" void kernel_launch(void* const* d_in, const int* in_sizes, int n_in,
                              void* d_out, int out_size, void* d_ws, size_t ws_size,
                              hipStream_t stream) {
    const float* y        = (const float*)d_in[0];
    const int*   src      = (const int*)d_in[1];
    const int*   dst      = (const int*)d_in[2];
    const int*   n_nodes  = (const int*)d_in[3];
    const float* ln_g     = (const float*)d_in[4];
    const float* ln_b     = (const float*)d_in[5];
    const float* Wl       = (const float*)d_in[6];
    const float* bl       = (const float*)d_in[7];
    const float* Wr       = (const float*)d_in[8];
    const float* br       = (const float*)d_in[9];
    const float* ln2_g    = (const float*)d_in[10];
    const float* ln2_b    = (const float*)d_in[11];
    const float* W1       = (const float*)d_in[12];
    const float* b1       = (const float*)d_in[13];
    const float* W2       = (const float*)d_in[14];
    const float* b2       = (const float*)d_in[15];
    float* out = (float*)d_out;
    float* ws  = (float*)d_ws;

    const int E = in_sizes[0] / HDIM;

    zero_ws_kernel<<<2048, 256, 0, stream>>>(ws, n_nodes);
    gates_kernel<<<(E + 63) / 64, 256, 0, stream>>>(y, dst, ln_g, ln_b, Wl, bl, Wr, br,
                                                    ws, n_nodes, E);
    rdenom_kernel<<<256, 256, 0, stream>>>(ws, n_nodes);
    mlp_kernel<<<(E + 31) / 32, 256, 0, stream>>>(src, dst, ln2_g, ln2_b, W1, b1, W2, b2,
                                                  ws, n_nodes, out, E);
}

// Round 2
// 15880.730 us; speedup vs baseline: 1.2980x; 1.2980x over previous
//
#include <hip/hip_runtime.h>
#include <hip/hip_bf16.h>

#define HDIM 128
#define LN_EPS 1e-5f

__device__ __forceinline__ float sigmoidf_(float x) {
    return 1.0f / (1.0f + __expf(-x));
}

// ws layout (computed on device; N only known there):
//   float aggL[N*128]; float aggR[N*128]; float rd[N];
//   int ideg[N]; int ioff[N+1]; int icur[N]; int elist[E];
struct WsPtrs {
    float *aggL, *aggR, *rd;
    int *ideg, *ioff, *icur, *elist;
    int N;
};
__device__ __forceinline__ WsPtrs ws_ptrs(float* ws, const int* n_nodes_p) {
    WsPtrs p;
    p.N    = *n_nodes_p;
    p.aggL = ws;
    p.aggR = ws + (size_t)p.N * 128;
    p.rd   = ws + (size_t)p.N * 256;
    p.ideg = (int*)(ws + (size_t)p.N * 257);
    p.ioff = p.ideg + p.N;
    p.icur = p.ioff + p.N + 1;
    p.elist = p.icur + p.N;
    return p;
}

// ---------------- zero agg + deg ----------------
__global__ void init_kernel(float* __restrict__ ws, const int* __restrict__ n_nodes_p) {
    WsPtrs p = ws_ptrs(ws, n_nodes_p);
    const long long stride = (long long)gridDim.x * blockDim.x;
    const long long tid = (long long)blockIdx.x * blockDim.x + threadIdx.x;
    const long long nf = (long long)p.N * 256;
    for (long long i = tid; i < nf; i += stride) ws[i] = 0.0f;
    for (long long i = tid; i < p.N; i += stride) p.ideg[i] = 0;
}

// ---------------- histogram of dst ----------------
__global__ void hist_kernel(const int* __restrict__ dst, float* __restrict__ ws,
                            const int* __restrict__ n_nodes_p, int E) {
    WsPtrs p = ws_ptrs(ws, n_nodes_p);
    const int i = blockIdx.x * blockDim.x + threadIdx.x;
    if (i < E) atomicAdd(&p.ideg[dst[i]], 1);
}

// ---------------- exclusive scan (single block), also rd = 1/max(deg,1) ----------------
__global__ __launch_bounds__(256) void scan_kernel(float* __restrict__ ws,
                                                   const int* __restrict__ n_nodes_p) {
    WsPtrs p = ws_ptrs(ws, n_nodes_p);
    __shared__ int wsum[4];
    __shared__ int carry_s;
    const int t = threadIdx.x;
    const int lane = t & 63, wid = t >> 6;
    if (t == 0) carry_s = 0;
    __syncthreads();
    for (int base = 0; base < p.N; base += 1024) {
        const int i0 = base + t * 4;
        const int v0 = (i0 + 0 < p.N) ? p.ideg[i0 + 0] : 0;
        const int v1 = (i0 + 1 < p.N) ? p.ideg[i0 + 1] : 0;
        const int v2 = (i0 + 2 < p.N) ? p.ideg[i0 + 2] : 0;
        const int v3 = (i0 + 3 < p.N) ? p.ideg[i0 + 3] : 0;
        const int s = v0 + v1 + v2 + v3;
        int sc = s;
        #pragma unroll
        for (int off = 1; off < 64; off <<= 1) {
            const int n = __shfl_up(sc, off);
            if (lane >= off) sc += n;
        }
        if (lane == 63) wsum[wid] = sc;
        __syncthreads();
        int woff = 0;
        #pragma unroll
        for (int w = 0; w < 4; ++w) if (w < wid) woff += wsum[w];
        const int carry = carry_s;
        __syncthreads();
        const int excl = carry + woff + (sc - s);
        if (i0 + 0 < p.N) { p.ioff[i0+0] = excl;          p.icur[i0+0] = excl;          p.rd[i0+0] = 1.0f / fmaxf((float)v0, 1.0f); }
        if (i0 + 1 < p.N) { p.ioff[i0+1] = excl+v0;       p.icur[i0+1] = excl+v0;       p.rd[i0+1] = 1.0f / fmaxf((float)v1, 1.0f); }
        if (i0 + 2 < p.N) { p.ioff[i0+2] = excl+v0+v1;    p.icur[i0+2] = excl+v0+v1;    p.rd[i0+2] = 1.0f / fmaxf((float)v2, 1.0f); }
        if (i0 + 3 < p.N) { p.ioff[i0+3] = excl+v0+v1+v2; p.icur[i0+3] = excl+v0+v1+v2; p.rd[i0+3] = 1.0f / fmaxf((float)v3, 1.0f); }
        if (t == 255) carry_s = carry + woff + sc;
        __syncthreads();
    }
    if (t == 0) p.ioff[p.N] = carry_s;
}

// ---------------- scatter edge ids into buckets ----------------
__global__ void scatter_kernel(const int* __restrict__ dst, float* __restrict__ ws,
                               const int* __restrict__ n_nodes_p, int E) {
    WsPtrs p = ws_ptrs(ws, n_nodes_p);
    const int i = blockIdx.x * blockDim.x + threadIdx.x;
    if (i < E) {
        const int pos = atomicAdd(&p.icur[dst[i]], 1);
        p.elist[pos] = i;
    }
}

// ---------------- per-bucket insertion sort (deterministic order) ----------------
__global__ void bsort_kernel(float* __restrict__ ws, const int* __restrict__ n_nodes_p) {
    WsPtrs p = ws_ptrs(ws, n_nodes_p);
    const int stride = gridDim.x * blockDim.x;
    for (int i = blockIdx.x * blockDim.x + threadIdx.x; i < p.N; i += stride) {
        const int beg = p.ioff[i], end = p.ioff[i + 1];
        for (int a = beg + 1; a < end; ++a) {
            const int key = p.elist[a];
            int b = a - 1;
            while (b >= beg && p.elist[b] > key) { p.elist[b + 1] = p.elist[b]; --b; }
            p.elist[b + 1] = key;
        }
    }
}

// ---------------- LN + dual gate GEMM + sigmoid + run-compressed scatter ----------------
// block = 256 threads, 64 dst-sorted edges per block
__global__ __launch_bounds__(256) void gates_kernel(
    const float* __restrict__ y, const int* __restrict__ dst,
    const float* __restrict__ ln_g, const float* __restrict__ ln_b,
    const float* __restrict__ Wl, const float* __restrict__ bl,
    const float* __restrict__ Wr, const float* __restrict__ br,
    float* __restrict__ ws, const int* __restrict__ n_nodes_p, int E)
{
    __shared__ float sYn[64][129];
    __shared__ float sW[32][128];
    __shared__ int sNode[64];
    __shared__ int sEid[64];

    WsPtrs p = ws_ptrs(ws, n_nodes_p);
    const int t  = threadIdx.x;
    const int s0 = blockIdx.x * 64;

    if (t < 64) {
        const int j = s0 + t;
        const int eid = (j < E) ? p.elist[j] : -1;
        sEid[t]  = eid;
        sNode[t] = (eid >= 0) ? dst[eid] : -1;
    }
    __syncthreads();

    // --- LayerNorm: 4 threads per row ---
    {
        const int r = t >> 2, sub = t & 3;
        const int eid = sEid[r];
        const float* yr = y + (size_t)(eid >= 0 ? eid : 0) * HDIM;
        float v[32];
        #pragma unroll
        for (int j = 0; j < 8; ++j) {
            const float4 q = *reinterpret_cast<const float4*>(yr + 4 * sub + 16 * j);
            v[4*j+0] = q.x; v[4*j+1] = q.y; v[4*j+2] = q.z; v[4*j+3] = q.w;
        }
        float s = 0.f, sq = 0.f;
        #pragma unroll
        for (int j = 0; j < 32; ++j) { s += v[j]; sq += v[j] * v[j]; }
        s  += __shfl_xor(s, 1);  s  += __shfl_xor(s, 2);
        sq += __shfl_xor(sq, 1); sq += __shfl_xor(sq, 2);
        const float mu   = s * (1.0f / 128.0f);
        const float var  = sq * (1.0f / 128.0f) - mu * mu;
        const float rstd = rsqrtf(var + LN_EPS);
        #pragma unroll
        for (int j = 0; j < 8; ++j) {
            #pragma unroll
            for (int m = 0; m < 4; ++m) {
                const int c = 4 * sub + 16 * j + m;
                sYn[r][c] = (v[4*j+m] - mu) * rstd * ln_g[c] + ln_b[c];
            }
        }
    }

    const int cq = t & 31;   // output col quad
    const int er = t >> 5;   // edge group 0..7

    for (int g = 0; g < 2; ++g) {
        const float* W  = (g == 0) ? Wl : Wr;
        const float* bb_ = (g == 0) ? bl : br;
        float* ag       = (g == 0) ? p.aggL : p.aggR;

        float4 acc[8];
        #pragma unroll
        for (int i = 0; i < 8; ++i) acc[i] = make_float4(0.f, 0.f, 0.f, 0.f);

        for (int ch = 0; ch < 4; ++ch) {
            __syncthreads();
            #pragma unroll
            for (int i = 0; i < 4; ++i) {
                const int idx  = i * 256 + t;
                const int row  = idx >> 5;
                const int col4 = (idx & 31) << 2;
                *reinterpret_cast<float4*>(&sW[row][col4]) =
                    *reinterpret_cast<const float4*>(W + (size_t)(ch * 32 + row) * HDIM + col4);
            }
            __syncthreads();
            for (int kk = 0; kk < 32; ++kk) {
                const float4 w = *reinterpret_cast<const float4*>(&sW[kk][cq << 2]);
                #pragma unroll
                for (int i = 0; i < 8; ++i) {
                    const float a = sYn[er * 8 + i][ch * 32 + kk];
                    acc[i].x = fmaf(a, w.x, acc[i].x);
                    acc[i].y = fmaf(a, w.y, acc[i].y);
                    acc[i].z = fmaf(a, w.z, acc[i].z);
                    acc[i].w = fmaf(a, w.w, acc[i].w);
                }
            }
        }

        const float4 bq = *reinterpret_cast<const float4*>(bb_ + (cq << 2));
        // run-compressed atomic flush over this thread's 8 sorted edges
        float4 run = make_float4(0.f, 0.f, 0.f, 0.f);
        int rnode = -1;
        #pragma unroll
        for (int i = 0; i < 8; ++i) {
            const int node = sNode[er * 8 + i];
            float4 v;
            v.x = sigmoidf_(acc[i].x + bq.x);
            v.y = sigmoidf_(acc[i].y + bq.y);
            v.z = sigmoidf_(acc[i].z + bq.z);
            v.w = sigmoidf_(acc[i].w + bq.w);
            if (node != rnode) {
                if (rnode >= 0) {
                    float* dest = ag + (size_t)rnode * HDIM + (cq << 2);
                    atomicAdd(dest + 0, run.x);
                    atomicAdd(dest + 1, run.y);
                    atomicAdd(dest + 2, run.z);
                    atomicAdd(dest + 3, run.w);
                }
                run = v; rnode = node;
            } else {
                run.x += v.x; run.y += v.y; run.z += v.z; run.w += v.w;
            }
        }
        if (rnode >= 0) {
            float* dest = ag + (size_t)rnode * HDIM + (cq << 2);
            atomicAdd(dest + 0, run.x);
            atomicAdd(dest + 1, run.y);
            atomicAdd(dest + 2, run.z);
            atomicAdd(dest + 3, run.w);
        }
    }
}

// ---------------- gather + LN(256) + MLP GEMM + ELU + dot ----------------
// block = 256 threads, 32 edges per block
__global__ __launch_bounds__(256) void mlp_kernel(
    const int* __restrict__ src, const int* __restrict__ dst,
    const float* __restrict__ ln2_g, const float* __restrict__ ln2_b,
    const float* __restrict__ W1, const float* __restrict__ b1,
    const float* __restrict__ W2, const float* __restrict__ b2,
    const float* __restrict__ ws, const int* __restrict__ n_nodes_p,
    float* __restrict__ out, int E)
{
    __shared__ float sH[32][264];
    __shared__ float sW[32][128];

    const int N = *n_nodes_p;
    const float* aggL = ws;
    const float* aggR = ws + (size_t)N * 128;
    const float* rd   = ws + (size_t)N * 256;

    const int t  = threadIdx.x;
    const int e0 = blockIdx.x * 32;

    {
        const int hr   = t >> 2;
        const int sub  = t & 3;
        const int er_  = hr & 31;
        const int half = hr >> 5;
        const int e    = e0 + er_;
        if (e < E) {
            const int node = (half == 0) ? src[e] : dst[e];
            const float* srow = ((half == 0) ? aggL : aggR) + (size_t)node * HDIM;
            const float scale = rd[node];
            #pragma unroll
            for (int j = 0; j < 8; ++j) {
                float4 q = *reinterpret_cast<const float4*>(srow + 4 * sub + 16 * j);
                q.x *= scale; q.y *= scale; q.z *= scale; q.w *= scale;
                *reinterpret_cast<float4*>(&sH[er_][half * HDIM + 4 * sub + 16 * j]) = q;
            }
        } else {
            #pragma unroll
            for (int j = 0; j < 8; ++j)
                *reinterpret_cast<float4*>(&sH[er_][half * HDIM + 4 * sub + 16 * j]) =
                    make_float4(0.f, 0.f, 0.f, 0.f);
        }
    }
    __syncthreads();

    {
        const int r   = t >> 3;
        const int oct = t & 7;
        float vv[32];
        float s = 0.f, sq = 0.f;
        #pragma unroll
        for (int j = 0; j < 32; ++j) {
            const float x = sH[r][oct + 8 * j];
            vv[j] = x; s += x; sq += x * x;
        }
        s  += __shfl_xor(s, 1);  s  += __shfl_xor(s, 2);  s  += __shfl_xor(s, 4);
        sq += __shfl_xor(sq, 1); sq += __shfl_xor(sq, 2); sq += __shfl_xor(sq, 4);
        const float mu   = s * (1.0f / 256.0f);
        const float var  = sq * (1.0f / 256.0f) - mu * mu;
        const float rstd = rsqrtf(var + LN_EPS);
        #pragma unroll
        for (int j = 0; j < 32; ++j) {
            const int c = oct + 8 * j;
            sH[r][c] = (vv[j] - mu) * rstd * ln2_g[c] + ln2_b[c];
        }
    }
    __syncthreads();

    const int cq = t & 31;
    const int er = t >> 5;

    float4 acc[4];
    #pragma unroll
    for (int i = 0; i < 4; ++i) acc[i] = make_float4(0.f, 0.f, 0.f, 0.f);

    for (int ch = 0; ch < 8; ++ch) {
        __syncthreads();
        #pragma unroll
        for (int i = 0; i < 4; ++i) {
            const int idx  = i * 256 + t;
            const int row  = idx >> 5;
            const int col4 = (idx & 31) << 2;
            *reinterpret_cast<float4*>(&sW[row][col4]) =
                *reinterpret_cast<const float4*>(W1 + (size_t)(ch * 32 + row) * HDIM + col4);
        }
        __syncthreads();
        for (int kk = 0; kk < 32; ++kk) {
            const float4 w = *reinterpret_cast<const float4*>(&sW[kk][cq << 2]);
            #pragma unroll
            for (int i = 0; i < 4; ++i) {
                const float a = sH[er + 8 * i][ch * 32 + kk];
                acc[i].x = fmaf(a, w.x, acc[i].x);
                acc[i].y = fmaf(a, w.y, acc[i].y);
                acc[i].z = fmaf(a, w.z, acc[i].z);
                acc[i].w = fmaf(a, w.w, acc[i].w);
            }
        }
    }

    const float4 b1q = *reinterpret_cast<const float4*>(b1 + (cq << 2));
    const float4 w2q = *reinterpret_cast<const float4*>(W2 + (cq << 2));
    const float bias2 = b2[0];
    #pragma unroll
    for (int i = 0; i < 4; ++i) {
        float4 u = acc[i];
        u.x += b1q.x; u.y += b1q.y; u.z += b1q.z; u.w += b1q.w;
        u.x = u.x > 0.f ? u.x : __expf(u.x) - 1.f;
        u.y = u.y > 0.f ? u.y : __expf(u.y) - 1.f;
        u.z = u.z > 0.f ? u.z : __expf(u.z) - 1.f;
        u.w = u.w > 0.f ? u.w : __expf(u.w) - 1.f;
        float pp = u.x * w2q.x + u.y * w2q.y + u.z * w2q.z + u.w * w2q.w;
        #pragma unroll
        for (int m = 16; m >= 1; m >>= 1) pp += __shfl_xor(pp, m);
        if (cq == 0) {
            const int e = e0 + er + 8 * i;
            if (e < E) out[e] = pp + bias2;
        }
    }
}

extern "C" void kernel_launch(void* const* d_in, const int* in_sizes, int n_in,
                              void* d_out, int out_size, void* d_ws, size_t ws_size,
                              hipStream_t stream) {
    const float* y        = (const float*)d_in[0];
    const int*   src      = (const int*)d_in[1];
    const int*   dst      = (const int*)d_in[2];
    const int*   n_nodes  = (const int*)d_in[3];
    const float* ln_g     = (const float*)d_in[4];
    const float* ln_b     = (const float*)d_in[5];
    const float* Wl       = (const float*)d_in[6];
    const float* bl       = (const float*)d_in[7];
    const float* Wr       = (const float*)d_in[8];
    const float* br       = (const float*)d_in[9];
    const float* ln2_g    = (const float*)d_in[10];
    const float* ln2_b    = (const float*)d_in[11];
    const float* W1       = (const float*)d_in[12];
    const float* b1       = (const float*)d_in[13];
    const float* W2       = (const float*)d_in[14];
    const float* b2       = (const float*)d_in[15];
    float* out = (float*)d_out;
    float* ws  = (float*)d_ws;

    const int E = in_sizes[0] / HDIM;

    init_kernel<<<2048, 256, 0, stream>>>(ws, n_nodes);
    hist_kernel<<<(E + 255) / 256, 256, 0, stream>>>(dst, ws, n_nodes, E);
    scan_kernel<<<1, 256, 0, stream>>>(ws, n_nodes);
    scatter_kernel<<<(E + 255) / 256, 256, 0, stream>>>(dst, ws, n_nodes, E);
    bsort_kernel<<<512, 256, 0, stream>>>(ws, n_nodes);
    gates_kernel<<<(E + 63) / 64, 256, 0, stream>>>(y, dst, ln_g, ln_b, Wl, bl, Wr, br,
                                                    ws, n_nodes, E);
    mlp_kernel<<<(E + 31) / 32, 256, 0, stream>>>(src, dst, ln2_g, ln2_b, W1, b1, W2, b2,
                                                  ws, n_nodes, out, E);
}

// Round 3
// 1058.011 us; speedup vs baseline: 19.4831x; 15.0100x over previous
//
#include <hip/hip_runtime.h>
#include <hip/hip_bf16.h>

#define LN_EPS 1e-5f

typedef __attribute__((ext_vector_type(8))) short bf16x8;
typedef __attribute__((ext_vector_type(4))) float f32x4;

__device__ __forceinline__ float sigmoidf_(float x) { return 1.0f / (1.0f + __expf(-x)); }
__device__ __forceinline__ ushort f2bf(float x) {
    __hip_bfloat16 h = __float2bfloat16(x);   // RNE
    return __builtin_bit_cast(ushort, h);
}

// ws layout (N read on device):
//   float aggL[N*128]; float aggR[N*128]; float rd[N];
//   int ideg[N]; int ioff[N+1]; int icur[N]; int elist[E];
//   ushort WTg[256*128] (16B-aligned); ushort WT1[128*256];
struct WsPtrs {
    float *aggL, *aggR, *rd;
    int *ideg, *ioff, *icur, *elist;
    ushort *WTg, *WT1;
    int N;
};
__device__ __forceinline__ WsPtrs ws_ptrs(float* ws, const int* n_nodes_p, int E) {
    WsPtrs p;
    p.N    = *n_nodes_p;
    p.aggL = ws;
    p.aggR = ws + (size_t)p.N * 128;
    p.rd   = ws + (size_t)p.N * 256;
    p.ideg = (int*)(ws + (size_t)p.N * 257);
    p.ioff = p.ideg + p.N;
    p.icur = p.ioff + p.N + 1;
    p.elist = p.icur + p.N;
    p.WTg = (ushort*)(((uintptr_t)(p.elist + E) + 15) & ~(uintptr_t)15);
    p.WT1 = p.WTg + 256 * 128;
    return p;
}

// ---------------- zero agg + deg ----------------
__global__ void init_kernel(float* __restrict__ ws, const int* __restrict__ n_nodes_p, int E) {
    WsPtrs p = ws_ptrs(ws, n_nodes_p, E);
    const long long stride = (long long)gridDim.x * blockDim.x;
    const long long tid = (long long)blockIdx.x * blockDim.x + threadIdx.x;
    const long long nf = (long long)p.N * 256;
    for (long long i = tid; i < nf; i += stride) ws[i] = 0.0f;
    for (long long i = tid; i < p.N; i += stride) p.ideg[i] = 0;
}

// ---------------- histogram of dst ----------------
__global__ void hist_kernel(const int* __restrict__ dst, float* __restrict__ ws,
                            const int* __restrict__ n_nodes_p, int E) {
    WsPtrs p = ws_ptrs(ws, n_nodes_p, E);
    const int i = blockIdx.x * blockDim.x + threadIdx.x;
    if (i < E) atomicAdd(&p.ideg[dst[i]], 1);
}

// ---------------- exclusive scan (single block) + rd = 1/max(deg,1) ----------------
__global__ __launch_bounds__(256) void scan_kernel(float* __restrict__ ws,
                                                   const int* __restrict__ n_nodes_p, int E) {
    WsPtrs p = ws_ptrs(ws, n_nodes_p, E);
    __shared__ int wsum[4];
    __shared__ int carry_s;
    const int t = threadIdx.x;
    const int lane = t & 63, wid = t >> 6;
    if (t == 0) carry_s = 0;
    __syncthreads();
    for (int base = 0; base < p.N; base += 1024) {
        const int i0 = base + t * 4;
        const int v0 = (i0 + 0 < p.N) ? p.ideg[i0 + 0] : 0;
        const int v1 = (i0 + 1 < p.N) ? p.ideg[i0 + 1] : 0;
        const int v2 = (i0 + 2 < p.N) ? p.ideg[i0 + 2] : 0;
        const int v3 = (i0 + 3 < p.N) ? p.ideg[i0 + 3] : 0;
        const int s = v0 + v1 + v2 + v3;
        int sc = s;
        #pragma unroll
        for (int off = 1; off < 64; off <<= 1) {
            const int n = __shfl_up(sc, off);
            if (lane >= off) sc += n;
        }
        if (lane == 63) wsum[wid] = sc;
        __syncthreads();
        int woff = 0;
        #pragma unroll
        for (int w = 0; w < 4; ++w) if (w < wid) woff += wsum[w];
        const int carry = carry_s;
        __syncthreads();
        const int excl = carry + woff + (sc - s);
        if (i0 + 0 < p.N) { p.ioff[i0+0] = excl;          p.icur[i0+0] = excl;          p.rd[i0+0] = 1.0f / fmaxf((float)v0, 1.0f); }
        if (i0 + 1 < p.N) { p.ioff[i0+1] = excl+v0;       p.icur[i0+1] = excl+v0;       p.rd[i0+1] = 1.0f / fmaxf((float)v1, 1.0f); }
        if (i0 + 2 < p.N) { p.ioff[i0+2] = excl+v0+v1;    p.icur[i0+2] = excl+v0+v1;    p.rd[i0+2] = 1.0f / fmaxf((float)v2, 1.0f); }
        if (i0 + 3 < p.N) { p.ioff[i0+3] = excl+v0+v1+v2; p.icur[i0+3] = excl+v0+v1+v2; p.rd[i0+3] = 1.0f / fmaxf((float)v3, 1.0f); }
        if (t == 255) carry_s = carry + woff + sc;
        __syncthreads();
    }
    if (t == 0) p.ioff[p.N] = carry_s;
}

// ---------------- scatter edge ids into buckets ----------------
__global__ void scatter_kernel(const int* __restrict__ dst, float* __restrict__ ws,
                               const int* __restrict__ n_nodes_p, int E) {
    WsPtrs p = ws_ptrs(ws, n_nodes_p, E);
    const int i = blockIdx.x * blockDim.x + threadIdx.x;
    if (i < E) {
        const int pos = atomicAdd(&p.icur[dst[i]], 1);
        p.elist[pos] = i;
    }
}

// ---------------- per-bucket insertion sort (deterministic order) ----------------
__global__ void bsort_kernel(float* __restrict__ ws, const int* __restrict__ n_nodes_p, int E) {
    WsPtrs p = ws_ptrs(ws, n_nodes_p, E);
    const int stride = gridDim.x * blockDim.x;
    for (int i = blockIdx.x * blockDim.x + threadIdx.x; i < p.N; i += stride) {
        const int beg = p.ioff[i], end = p.ioff[i + 1];
        for (int a = beg + 1; a < end; ++a) {
            const int key = p.elist[a];
            int b = a - 1;
            while (b >= beg && p.elist[b] > key) { p.elist[b + 1] = p.elist[b]; --b; }
            p.elist[b + 1] = key;
        }
    }
}

// ---------------- transpose weights to bf16, K-contiguous per output col ----------------
__global__ void prep_w_kernel(const float* __restrict__ Wl, const float* __restrict__ Wr,
                              const float* __restrict__ W1,
                              float* __restrict__ ws, const int* __restrict__ n_nodes_p, int E) {
    WsPtrs p = ws_ptrs(ws, n_nodes_p, E);
    const int i = blockIdx.x * blockDim.x + threadIdx.x;
    if (i < 32768) {                       // WTg[n][k] = (n<128?Wl:Wr)[k][n&127]
        const int n = i >> 7, k = i & 127;
        const float val = (n < 128) ? Wl[k * 128 + n] : Wr[k * 128 + (n - 128)];
        p.WTg[i] = f2bf(val);
    } else if (i < 65536) {                // WT1[n][k] = W1[k][n]
        const int j = i - 32768;
        const int n = j >> 8, k = j & 255;
        p.WT1[j] = f2bf(W1[k * 128 + n]);
    }
}

// ---------------- gates: LN + MFMA dual-gate GEMM + sigmoid + compressed scatter ----------------
// block = 256 (4 waves), 64 dst-sorted edges. Wave w owns output cols [w*64, w*64+64).
__global__ __launch_bounds__(256) void gates_kernel(
    const float* __restrict__ y, const int* __restrict__ dst,
    const float* __restrict__ ln_g, const float* __restrict__ ln_b,
    const float* __restrict__ bl, const float* __restrict__ br,
    float* __restrict__ ws, const int* __restrict__ n_nodes_p, int E)
{
    __shared__ ushort sA[64 * 128];   // yn bf16, fragment-chunk layout (16 KB)
    __shared__ ushort sB[128 * 128];  // half-K of WTg, fragment-chunk layout (32 KB)
    __shared__ int sNode[64];
    __shared__ int sEid[64];

    WsPtrs p = ws_ptrs(ws, n_nodes_p, E);
    const int t = threadIdx.x;
    const int s0 = blockIdx.x * 64;

    if (t < 64) {
        const int j = s0 + t;
        const int eid = (j < E) ? p.elist[j] : -1;
        sEid[t] = eid;
        sNode[t] = (eid >= 0) ? dst[eid] : -1;
    }
    __syncthreads();

    // LayerNorm -> sA bf16 chunks. 4 threads/row, sub owns cols [32*sub, 32*sub+32).
    // chunk(col8, row) = (col8>>2)*256 + (col8&3)*64 + row, 16B per chunk.
    {
        const int r = t >> 2, sub = t & 3;
        const int eid = sEid[r];
        const float* yr = y + (size_t)(eid >= 0 ? eid : 0) * 128;
        float v[32];
        float s = 0.f, sq = 0.f;
        #pragma unroll
        for (int i = 0; i < 8; ++i) {
            const float4 q = *reinterpret_cast<const float4*>(yr + sub * 32 + i * 4);
            v[i*4+0] = q.x; v[i*4+1] = q.y; v[i*4+2] = q.z; v[i*4+3] = q.w;
            s  += q.x + q.y + q.z + q.w;
            sq += q.x*q.x + q.y*q.y + q.z*q.z + q.w*q.w;
        }
        s  += __shfl_xor(s, 1);  s  += __shfl_xor(s, 2);
        sq += __shfl_xor(sq, 1); sq += __shfl_xor(sq, 2);
        const float mu = s * (1.f / 128.f);
        const float rstd = rsqrtf(sq * (1.f / 128.f) - mu * mu + LN_EPS);
        #pragma unroll
        for (int i = 0; i < 4; ++i) {
            uint w32[4];
            #pragma unroll
            for (int h2 = 0; h2 < 4; ++h2) {
                const int c = sub * 32 + i * 8 + h2 * 2;
                const float x0 = (v[i*8 + h2*2 + 0] - mu) * rstd * ln_g[c + 0] + ln_b[c + 0];
                const float x1 = (v[i*8 + h2*2 + 1] - mu) * rstd * ln_g[c + 1] + ln_b[c + 1];
                w32[h2] = (uint)f2bf(x0) | ((uint)f2bf(x1) << 16);
            }
            const int chunk = sub * 256 + i * 64 + r;   // col8 = sub*4 + i
            *reinterpret_cast<uint4*>(sA + chunk * 8) = make_uint4(w32[0], w32[1], w32[2], w32[3]);
        }
    }

    const int lane = t & 63;
    const int w = t >> 6;
    const int lhi = lane >> 4, llo = lane & 15;

    f32x4 acc[4][4];
    #pragma unroll
    for (int m = 0; m < 4; ++m)
        #pragma unroll
        for (int n = 0; n < 4; ++n) acc[m][n] = (f32x4){0.f, 0.f, 0.f, 0.f};

    #pragma unroll
    for (int h = 0; h < 2; ++h) {
        __syncthreads();
        // stage WTg k8 in [8h, 8h+8): cB(n, k8l) = (n>>4)*128 + (k8l>>2)*64 + (k8l&3)*16 + (n&15)
        #pragma unroll
        for (int I = 0; I < 8; ++I) {
            const int G = I * 256 + t;
            const int n = G >> 3, k8l = G & 7;
            const int cB = ((n >> 4) << 7) + ((k8l >> 2) << 6) + ((k8l & 3) << 4) + (n & 15);
            *reinterpret_cast<uint4*>(sB + cB * 8) =
                *reinterpret_cast<const uint4*>(p.WTg + ((size_t)n * 16 + h * 8 + k8l) * 8);
        }
        __syncthreads();
        #pragma unroll
        for (int kfl = 0; kfl < 2; ++kfl) {
            const int kf = h * 2 + kfl;
            bf16x8 a[4], b[4];
            #pragma unroll
            for (int m = 0; m < 4; ++m) {
                const int chunk = kf * 256 + lhi * 64 + m * 16 + llo;
                a[m] = *reinterpret_cast<const bf16x8*>(sA + chunk * 8);
            }
            #pragma unroll
            for (int nf = 0; nf < 4; ++nf) {
                const int nblk = w * 4 + nf;
                const int cB = nblk * 128 + kfl * 64 + lhi * 16 + llo;
                b[nf] = *reinterpret_cast<const bf16x8*>(sB + cB * 8);
            }
            #pragma unroll
            for (int m = 0; m < 4; ++m)
                #pragma unroll
                for (int nf = 0; nf < 4; ++nf)
                    acc[m][nf] = __builtin_amdgcn_mfma_f32_16x16x32_bf16(a[m], b[nf], acc[m][nf], 0, 0, 0);
        }
    }

    // epilogue: sigmoid + run-compressed atomics. D: col=lane&15, row=(lane>>4)*4+j.
    const int g = w >> 1;
    float* ag = g ? p.aggR : p.aggL;
    const float* bp = g ? br : bl;
    #pragma unroll
    for (int nf = 0; nf < 4; ++nf) {
        const int col = w * 64 + nf * 16 + llo;
        const int lcol = col & 127;
        const float bias = bp[lcol];
        float runv = 0.f;
        int rnode = -1;
        #pragma unroll
        for (int m = 0; m < 4; ++m) {
            #pragma unroll
            for (int j = 0; j < 4; ++j) {
                const int el = m * 16 + lhi * 4 + j;
                const int node = sNode[el];
                const float val = sigmoidf_(acc[m][nf][j] + bias);
                if (node != rnode) {
                    if (rnode >= 0) atomicAdd(ag + (size_t)rnode * 128 + lcol, runv);
                    rnode = node;
                    runv = val;
                } else {
                    runv += val;
                }
            }
        }
        if (rnode >= 0) atomicAdd(ag + (size_t)rnode * 128 + lcol, runv);
    }
}

// ---------------- mlp: gather + LN(256) + MFMA GEMM + ELU + W2 dot ----------------
// block = 256 (4 waves), 64 edges. Wave w owns output cols [w*32, w*32+32).
__global__ __launch_bounds__(256) void mlp_kernel(
    const int* __restrict__ src, const int* __restrict__ dst,
    const float* __restrict__ ln2_g, const float* __restrict__ ln2_b,
    const float* __restrict__ b1, const float* __restrict__ W2,
    const float* __restrict__ b2,
    float* __restrict__ ws, const int* __restrict__ n_nodes_p,
    float* __restrict__ out, int E)
{
    __shared__ ushort sA[64 * 256];   // h bf16 chunks (32 KB)
    __shared__ ushort sB[128 * 128];  // half-K of WT1 (32 KB)
    __shared__ float sPart[4][64];

    WsPtrs p = ws_ptrs(ws, n_nodes_p, E);
    const int t = threadIdx.x;
    const int e0 = blockIdx.x * 64;

    // gather + LN(256) -> sA. 4 threads/row, sub owns cols [64*sub, 64*sub+64).
    {
        const int r = t >> 2, sub = t & 3;
        const int e = e0 + r;
        const bool vld = e < E;
        const int node = vld ? ((sub < 2) ? src[e] : dst[e]) : 0;
        const float* base = ((sub < 2) ? p.aggL : p.aggR) + (size_t)node * 128 + (sub & 1) * 64;
        const float scale = vld ? p.rd[node] : 0.f;
        float s = 0.f, sq = 0.f;
        #pragma unroll
        for (int i = 0; i < 16; ++i) {
            const float4 q = *reinterpret_cast<const float4*>(base + i * 4);
            const float x0 = q.x * scale, x1 = q.y * scale, x2 = q.z * scale, x3 = q.w * scale;
            s  += x0 + x1 + x2 + x3;
            sq += x0*x0 + x1*x1 + x2*x2 + x3*x3;
        }
        s  += __shfl_xor(s, 1);  s  += __shfl_xor(s, 2);
        sq += __shfl_xor(sq, 1); sq += __shfl_xor(sq, 2);
        const float mu = s * (1.f / 256.f);
        const float rstd = rsqrtf(sq * (1.f / 256.f) - mu * mu + LN_EPS);
        #pragma unroll
        for (int ii = 0; ii < 8; ++ii) {
            const float4 qa = *reinterpret_cast<const float4*>(base + ii * 8);
            const float4 qb = *reinterpret_cast<const float4*>(base + ii * 8 + 4);
            const float xs[8] = { qa.x*scale, qa.y*scale, qa.z*scale, qa.w*scale,
                                  qb.x*scale, qb.y*scale, qb.z*scale, qb.w*scale };
            uint w32[4];
            #pragma unroll
            for (int h2 = 0; h2 < 4; ++h2) {
                const int c = sub * 64 + ii * 8 + h2 * 2;
                const float x0 = (xs[h2*2 + 0] - mu) * rstd * ln2_g[c + 0] + ln2_b[c + 0];
                const float x1 = (xs[h2*2 + 1] - mu) * rstd * ln2_g[c + 1] + ln2_b[c + 1];
                w32[h2] = (uint)f2bf(x0) | ((uint)f2bf(x1) << 16);
            }
            const int col8 = sub * 8 + ii;
            const int chunk = ((col8 >> 2) << 8) + ((col8 & 3) << 6) + r;
            *reinterpret_cast<uint4*>(sA + chunk * 8) = make_uint4(w32[0], w32[1], w32[2], w32[3]);
        }
    }

    const int lane = t & 63;
    const int w = t >> 6;
    const int lhi = lane >> 4, llo = lane & 15;

    f32x4 acc[4][2];
    #pragma unroll
    for (int m = 0; m < 4; ++m)
        #pragma unroll
        for (int n = 0; n < 2; ++n) acc[m][n] = (f32x4){0.f, 0.f, 0.f, 0.f};

    #pragma unroll
    for (int h = 0; h < 2; ++h) {
        __syncthreads();
        // stage WT1 k8 in [16h, 16h+16): cB(n,k8l) = (n>>4)*256 + (k8l>>2)*64 + (k8l&3)*16 + (n&15)
        #pragma unroll
        for (int I = 0; I < 8; ++I) {
            const int G = I * 256 + t;
            const int n = G >> 4, k8l = G & 15;
            const int cB = ((n >> 4) << 8) + ((k8l >> 2) << 6) + ((k8l & 3) << 4) + (n & 15);
            *reinterpret_cast<uint4*>(sB + cB * 8) =
                *reinterpret_cast<const uint4*>(p.WT1 + ((size_t)n * 32 + h * 16 + k8l) * 8);
        }
        __syncthreads();
        #pragma unroll
        for (int kfl = 0; kfl < 4; ++kfl) {
            const int kf = h * 4 + kfl;
            bf16x8 a[4], b[2];
            #pragma unroll
            for (int m = 0; m < 4; ++m) {
                const int chunk = kf * 256 + lhi * 64 + m * 16 + llo;
                a[m] = *reinterpret_cast<const bf16x8*>(sA + chunk * 8);
            }
            #pragma unroll
            for (int nf = 0; nf < 2; ++nf) {
                const int nblk = w * 2 + nf;
                const int cB = nblk * 256 + kfl * 64 + lhi * 16 + llo;
                b[nf] = *reinterpret_cast<const bf16x8*>(sB + cB * 8);
            }
            #pragma unroll
            for (int m = 0; m < 4; ++m)
                #pragma unroll
                for (int nf = 0; nf < 2; ++nf)
                    acc[m][nf] = __builtin_amdgcn_mfma_f32_16x16x32_bf16(a[m], b[nf], acc[m][nf], 0, 0, 0);
        }
    }

    // epilogue: bias + ELU + dot(W2) + 16-lane reduce + cross-wave reduce
    float b1v[2], w2v[2];
    #pragma unroll
    for (int nf = 0; nf < 2; ++nf) {
        const int col = w * 32 + nf * 16 + llo;
        b1v[nf] = b1[col];
        w2v[nf] = W2[col];
    }
    #pragma unroll
    for (int m = 0; m < 4; ++m) {
        #pragma unroll
        for (int j = 0; j < 4; ++j) {
            float pr = 0.f;
            #pragma unroll
            for (int nf = 0; nf < 2; ++nf) {
                float x = acc[m][nf][j] + b1v[nf];
                x = x > 0.f ? x : (__expf(x) - 1.f);
                pr += x * w2v[nf];
            }
            pr += __shfl_xor(pr, 1); pr += __shfl_xor(pr, 2);
            pr += __shfl_xor(pr, 4); pr += __shfl_xor(pr, 8);
            if (llo == 0) sPart[w][m * 16 + lhi * 4 + j] = pr;
        }
    }
    __syncthreads();
    if (t < 64) {
        const int e = e0 + t;
        if (e < E) out[e] = sPart[0][t] + sPart[1][t] + sPart[2][t] + sPart[3][t] + b2[0];
    }
}

extern "C" void kernel_launch(void* const* d_in, const int* in_sizes, int n_in,
                              void* d_out, int out_size, void* d_ws, size_t ws_size,
                              hipStream_t stream) {
    const float* y       = (const float*)d_in[0];
    const int*   src     = (const int*)d_in[1];
    const int*   dst     = (const int*)d_in[2];
    const int*   n_nodes = (const int*)d_in[3];
    const float* ln_g    = (const float*)d_in[4];
    const float* ln_b    = (const float*)d_in[5];
    const float* Wl      = (const float*)d_in[6];
    const float* bl      = (const float*)d_in[7];
    const float* Wr      = (const float*)d_in[8];
    const float* br      = (const float*)d_in[9];
    const float* ln2_g   = (const float*)d_in[10];
    const float* ln2_b   = (const float*)d_in[11];
    const float* W1      = (const float*)d_in[12];
    const float* b1      = (const float*)d_in[13];
    const float* W2      = (const float*)d_in[14];
    const float* b2      = (const float*)d_in[15];
    float* out = (float*)d_out;
    float* ws  = (float*)d_ws;

    const int E = in_sizes[0] / 128;
    const int eb = (E + 63) / 64;

    init_kernel<<<2048, 256, 0, stream>>>(ws, n_nodes, E);
    hist_kernel<<<(E + 255) / 256, 256, 0, stream>>>(dst, ws, n_nodes, E);
    scan_kernel<<<1, 256, 0, stream>>>(ws, n_nodes, E);
    scatter_kernel<<<(E + 255) / 256, 256, 0, stream>>>(dst, ws, n_nodes, E);
    bsort_kernel<<<512, 256, 0, stream>>>(ws, n_nodes, E);
    prep_w_kernel<<<256, 256, 0, stream>>>(Wl, Wr, W1, ws, n_nodes, E);
    gates_kernel<<<eb, 256, 0, stream>>>(y, dst, ln_g, ln_b, bl, br, ws, n_nodes, E);
    mlp_kernel<<<eb, 256, 0, stream>>>(src, dst, ln2_g, ln2_b, b1, W2, b2, ws, n_nodes, out, E);
}

// Round 4
// 905.533 us; speedup vs baseline: 22.7637x; 1.1684x over previous
//
#include <hip/hip_runtime.h>
#include <hip/hip_bf16.h>

#define LN_EPS 1e-5f

typedef __attribute__((ext_vector_type(8))) short bf16x8;
typedef __attribute__((ext_vector_type(4))) float f32x4;

__device__ __forceinline__ float sigmoidf_(float x) { return 1.0f / (1.0f + __expf(-x)); }
__device__ __forceinline__ ushort f2bf(float x) {
    __hip_bfloat16 h = __float2bfloat16(x);   // RNE
    return __builtin_bit_cast(ushort, h);
}

// ws layout (N read on device):
//   float aggL[N*128]; float aggR[N*128]; float rd[N];
//   int ideg[N]; int ioff[N+1]; int icur[N]; int elist[E];
//   ushort WgF[16*4*64*8] (gates B fragments); ushort W1F[8*8*64*8] (mlp B fragments)
struct WsPtrs {
    float *aggL, *aggR, *rd;
    int *ideg, *ioff, *icur, *elist;
    ushort *WgF, *W1F;
    int N;
};
__device__ __forceinline__ WsPtrs ws_ptrs(float* ws, const int* n_nodes_p, int E) {
    WsPtrs p;
    p.N    = *n_nodes_p;
    p.aggL = ws;
    p.aggR = ws + (size_t)p.N * 128;
    p.rd   = ws + (size_t)p.N * 256;
    p.ideg = (int*)(ws + (size_t)p.N * 257);
    p.ioff = p.ideg + p.N;
    p.icur = p.ioff + p.N + 1;
    p.elist = p.icur + p.N;
    p.WgF = (ushort*)(((uintptr_t)(p.elist + E) + 15) & ~(uintptr_t)15);
    p.W1F = p.WgF + 32768;
    return p;
}

// ---------------- zero agg + deg ----------------
__global__ void init_kernel(float* __restrict__ ws, const int* __restrict__ n_nodes_p, int E) {
    WsPtrs p = ws_ptrs(ws, n_nodes_p, E);
    const long long stride = (long long)gridDim.x * blockDim.x;
    const long long tid = (long long)blockIdx.x * blockDim.x + threadIdx.x;
    const long long nf = (long long)p.N * 256;
    for (long long i = tid; i < nf; i += stride) ws[i] = 0.0f;
    for (long long i = tid; i < p.N; i += stride) p.ideg[i] = 0;
}

// ---------------- histogram of dst ----------------
__global__ void hist_kernel(const int* __restrict__ dst, float* __restrict__ ws,
                            const int* __restrict__ n_nodes_p, int E) {
    WsPtrs p = ws_ptrs(ws, n_nodes_p, E);
    const int i = blockIdx.x * blockDim.x + threadIdx.x;
    if (i < E) atomicAdd(&p.ideg[dst[i]], 1);
}

// ---------------- exclusive scan (single block) + rd = 1/max(deg,1) ----------------
__global__ __launch_bounds__(256) void scan_kernel(float* __restrict__ ws,
                                                   const int* __restrict__ n_nodes_p, int E) {
    WsPtrs p = ws_ptrs(ws, n_nodes_p, E);
    __shared__ int wsum[4];
    __shared__ int carry_s;
    const int t = threadIdx.x;
    const int lane = t & 63, wid = t >> 6;
    if (t == 0) carry_s = 0;
    __syncthreads();
    for (int base = 0; base < p.N; base += 1024) {
        const int i0 = base + t * 4;
        const int v0 = (i0 + 0 < p.N) ? p.ideg[i0 + 0] : 0;
        const int v1 = (i0 + 1 < p.N) ? p.ideg[i0 + 1] : 0;
        const int v2 = (i0 + 2 < p.N) ? p.ideg[i0 + 2] : 0;
        const int v3 = (i0 + 3 < p.N) ? p.ideg[i0 + 3] : 0;
        const int s = v0 + v1 + v2 + v3;
        int sc = s;
        #pragma unroll
        for (int off = 1; off < 64; off <<= 1) {
            const int n = __shfl_up(sc, off);
            if (lane >= off) sc += n;
        }
        if (lane == 63) wsum[wid] = sc;
        __syncthreads();
        int woff = 0;
        #pragma unroll
        for (int w = 0; w < 4; ++w) if (w < wid) woff += wsum[w];
        const int carry = carry_s;
        __syncthreads();
        const int excl = carry + woff + (sc - s);
        if (i0 + 0 < p.N) { p.ioff[i0+0] = excl;          p.icur[i0+0] = excl;          p.rd[i0+0] = 1.0f / fmaxf((float)v0, 1.0f); }
        if (i0 + 1 < p.N) { p.ioff[i0+1] = excl+v0;       p.icur[i0+1] = excl+v0;       p.rd[i0+1] = 1.0f / fmaxf((float)v1, 1.0f); }
        if (i0 + 2 < p.N) { p.ioff[i0+2] = excl+v0+v1;    p.icur[i0+2] = excl+v0+v1;    p.rd[i0+2] = 1.0f / fmaxf((float)v2, 1.0f); }
        if (i0 + 3 < p.N) { p.ioff[i0+3] = excl+v0+v1+v2; p.icur[i0+3] = excl+v0+v1+v2; p.rd[i0+3] = 1.0f / fmaxf((float)v3, 1.0f); }
        if (t == 255) carry_s = carry + woff + sc;
        __syncthreads();
    }
    if (t == 0) p.ioff[p.N] = carry_s;
}

// ---------------- scatter edge ids into buckets ----------------
__global__ void scatter_kernel(const int* __restrict__ dst, float* __restrict__ ws,
                               const int* __restrict__ n_nodes_p, int E) {
    WsPtrs p = ws_ptrs(ws, n_nodes_p, E);
    const int i = blockIdx.x * blockDim.x + threadIdx.x;
    if (i < E) {
        const int pos = atomicAdd(&p.icur[dst[i]], 1);
        p.elist[pos] = i;
    }
}

// ---------------- per-bucket insertion sort (deterministic order) ----------------
__global__ void bsort_kernel(float* __restrict__ ws, const int* __restrict__ n_nodes_p, int E) {
    WsPtrs p = ws_ptrs(ws, n_nodes_p, E);
    const int stride = gridDim.x * blockDim.x;
    for (int i = blockIdx.x * blockDim.x + threadIdx.x; i < p.N; i += stride) {
        const int beg = p.ioff[i], end = p.ioff[i + 1];
        for (int a = beg + 1; a < end; ++a) {
            const int key = p.elist[a];
            int b = a - 1;
            while (b >= beg && p.elist[b] > key) { p.elist[b + 1] = p.elist[b]; --b; }
            p.elist[b + 1] = key;
        }
    }
}

// ---------------- build fragment-major bf16 B tables ----------------
// WgF[nblk(16)][kf(4)][lane(64)][8]: value = W(k = kf*32 + (lane>>4)*8 + i, col = nblk*16 + (lane&15))
//   where W = Wl for col<128 else Wr (col-128).
// W1F[nblk(8)][kf(8)][lane(64)][8]: value = W1[k = kf*32 + (lane>>4)*8 + i][col = nblk*16 + (lane&15)]
__global__ void prep_w_kernel(const float* __restrict__ Wl, const float* __restrict__ Wr,
                              const float* __restrict__ W1,
                              float* __restrict__ ws, const int* __restrict__ n_nodes_p, int E) {
    WsPtrs p = ws_ptrs(ws, n_nodes_p, E);
    const int i = blockIdx.x * blockDim.x + threadIdx.x;
    if (i < 32768) {
        const int i8 = i & 7, lane = (i >> 3) & 63, kf = (i >> 9) & 3, nblk = i >> 11;
        const int k = kf * 32 + (lane >> 4) * 8 + i8;
        const int n = nblk * 16 + (lane & 15);
        const float val = (n < 128) ? Wl[k * 128 + n] : Wr[k * 128 + (n - 128)];
        p.WgF[i] = f2bf(val);
    } else if (i < 65536) {
        const int j = i - 32768;
        const int i8 = j & 7, lane = (j >> 3) & 63, kf = (j >> 9) & 7, nblk = j >> 12;
        const int k = kf * 32 + (lane >> 4) * 8 + i8;
        const int n = nblk * 16 + (lane & 15);
        p.W1F[j] = f2bf(W1[k * 128 + n]);
    }
}

// ---------------- gates: LN + MFMA dual-gate GEMM + sigmoid + compressed scatter ----------------
// block = 256 (4 waves), 64 dst-sorted edges. Wave w owns output cols [w*64, w*64+64).
// sA: linear [64 rows][128 cols] bf16, byte = row*256 + col*2, XOR-swizzle ((byte>>8)&7)<<4.
__global__ __launch_bounds__(256) void gates_kernel(
    const float* __restrict__ y, const int* __restrict__ dst,
    const float* __restrict__ ln_g, const float* __restrict__ ln_b,
    const float* __restrict__ bl, const float* __restrict__ br,
    float* __restrict__ ws, const int* __restrict__ n_nodes_p, int E)
{
    __shared__ ushort sA[64 * 128];   // 16 KB
    __shared__ int sNode[64];
    __shared__ int sEid[64];

    WsPtrs p = ws_ptrs(ws, n_nodes_p, E);
    char* sAb = reinterpret_cast<char*>(sA);
    const int t = threadIdx.x;
    const int s0 = blockIdx.x * 64;

    if (t < 64) {
        const int j = s0 + t;
        const int eid = (j < E) ? p.elist[j] : -1;
        sEid[t] = eid;
        sNode[t] = (eid >= 0) ? dst[eid] : -1;
    }
    __syncthreads();

    // LayerNorm -> sA. 4 threads/row, sub owns cols [32*sub, 32*sub+32).
    {
        const int r = t >> 2, sub = t & 3;
        const int eid = sEid[r];
        const float* yr = y + (size_t)(eid >= 0 ? eid : 0) * 128;
        float v[32];
        float s = 0.f, sq = 0.f;
        #pragma unroll
        for (int i = 0; i < 8; ++i) {
            const float4 q = *reinterpret_cast<const float4*>(yr + sub * 32 + i * 4);
            v[i*4+0] = q.x; v[i*4+1] = q.y; v[i*4+2] = q.z; v[i*4+3] = q.w;
            s  += q.x + q.y + q.z + q.w;
            sq += q.x*q.x + q.y*q.y + q.z*q.z + q.w*q.w;
        }
        s  += __shfl_xor(s, 1);  s  += __shfl_xor(s, 2);
        sq += __shfl_xor(sq, 1); sq += __shfl_xor(sq, 2);
        const float mu = s * (1.f / 128.f);
        const float rstd = rsqrtf(sq * (1.f / 128.f) - mu * mu + LN_EPS);
        #pragma unroll
        for (int i = 0; i < 4; ++i) {
            uint w32[4];
            #pragma unroll
            for (int h2 = 0; h2 < 4; ++h2) {
                const int c = sub * 32 + i * 8 + h2 * 2;
                const float x0 = (v[i*8 + h2*2 + 0] - mu) * rstd * ln_g[c + 0] + ln_b[c + 0];
                const float x1 = (v[i*8 + h2*2 + 1] - mu) * rstd * ln_g[c + 1] + ln_b[c + 1];
                w32[h2] = (uint)f2bf(x0) | ((uint)f2bf(x1) << 16);
            }
            int byte = r * 256 + sub * 64 + i * 16;
            byte ^= ((byte >> 8) & 7) << 4;
            *reinterpret_cast<uint4*>(sAb + byte) = make_uint4(w32[0], w32[1], w32[2], w32[3]);
        }
    }
    __syncthreads();

    const int lane = t & 63;
    const int w = t >> 6;
    const int lhi = lane >> 4, llo = lane & 15;

    f32x4 acc[4][4];
    #pragma unroll
    for (int m = 0; m < 4; ++m)
        #pragma unroll
        for (int n = 0; n < 4; ++n) acc[m][n] = (f32x4){0.f, 0.f, 0.f, 0.f};

    #pragma unroll
    for (int kf = 0; kf < 4; ++kf) {
        bf16x8 a[4], b[4];
        #pragma unroll
        for (int m = 0; m < 4; ++m) {
            const int row = m * 16 + llo;
            int byte = row * 256 + kf * 64 + lhi * 16;
            byte ^= ((byte >> 8) & 7) << 4;
            a[m] = *reinterpret_cast<const bf16x8*>(sAb + byte);
        }
        #pragma unroll
        for (int nf = 0; nf < 4; ++nf) {
            const int nblk = w * 4 + nf;
            b[nf] = *reinterpret_cast<const bf16x8*>(p.WgF + ((size_t)(nblk * 4 + kf) * 64 + lane) * 8);
        }
        #pragma unroll
        for (int m = 0; m < 4; ++m)
            #pragma unroll
            for (int nf = 0; nf < 4; ++nf)
                acc[m][nf] = __builtin_amdgcn_mfma_f32_16x16x32_bf16(a[m], b[nf], acc[m][nf], 0, 0, 0);
    }

    // epilogue: sigmoid + run-compressed atomics. D: col=lane&15, row=(lane>>4)*4+j.
    const int g = w >> 1;
    float* ag = g ? p.aggR : p.aggL;
    const float* bp = g ? br : bl;
    #pragma unroll
    for (int nf = 0; nf < 4; ++nf) {
        const int col = w * 64 + nf * 16 + llo;
        const int lcol = col & 127;
        const float bias = bp[lcol];
        float runv = 0.f;
        int rnode = -1;
        #pragma unroll
        for (int m = 0; m < 4; ++m) {
            #pragma unroll
            for (int j = 0; j < 4; ++j) {
                const int el = m * 16 + lhi * 4 + j;
                const int node = sNode[el];
                const float val = sigmoidf_(acc[m][nf][j] + bias);
                if (node != rnode) {
                    if (rnode >= 0) atomicAdd(ag + (size_t)rnode * 128 + lcol, runv);
                    rnode = node;
                    runv = val;
                } else {
                    runv += val;
                }
            }
        }
        if (rnode >= 0) atomicAdd(ag + (size_t)rnode * 128 + lcol, runv);
    }
}

// ---------------- mlp: gather + LN(256) + MFMA GEMM + ELU + W2 dot ----------------
// block = 256 (4 waves), 64 dst-sorted edges (elist order -> aggR rows L1-local).
// sA: linear [64 rows][256 cols] bf16, byte = row*512 + col*2, XOR-swizzle ((byte>>9)&7)<<4.
__global__ __launch_bounds__(256) void mlp_kernel(
    const int* __restrict__ src, const int* __restrict__ dst,
    const float* __restrict__ ln2_g, const float* __restrict__ ln2_b,
    const float* __restrict__ b1, const float* __restrict__ W2,
    const float* __restrict__ b2,
    float* __restrict__ ws, const int* __restrict__ n_nodes_p,
    float* __restrict__ out, int E)
{
    __shared__ ushort sA[64 * 256];   // 32 KB
    __shared__ float sPart[4][64];
    __shared__ int sEid[64];

    WsPtrs p = ws_ptrs(ws, n_nodes_p, E);
    char* sAb = reinterpret_cast<char*>(sA);
    const int t = threadIdx.x;
    const int s0 = blockIdx.x * 64;

    if (t < 64) {
        const int j = s0 + t;
        sEid[t] = (j < E) ? p.elist[j] : -1;
    }
    __syncthreads();

    // gather + LN(256) -> sA. 4 threads/row, sub owns cols [64*sub, 64*sub+64).
    {
        const int r = t >> 2, sub = t & 3;
        const int eid = sEid[r];
        const bool vld = eid >= 0;
        const int node = vld ? ((sub < 2) ? src[eid] : dst[eid]) : 0;
        const float* base = ((sub < 2) ? p.aggL : p.aggR) + (size_t)node * 128 + (sub & 1) * 64;
        const float scale = vld ? p.rd[node] : 0.f;
        float s = 0.f, sq = 0.f;
        #pragma unroll
        for (int i = 0; i < 16; ++i) {
            const float4 q = *reinterpret_cast<const float4*>(base + i * 4);
            const float x0 = q.x * scale, x1 = q.y * scale, x2 = q.z * scale, x3 = q.w * scale;
            s  += x0 + x1 + x2 + x3;
            sq += x0*x0 + x1*x1 + x2*x2 + x3*x3;
        }
        s  += __shfl_xor(s, 1);  s  += __shfl_xor(s, 2);
        sq += __shfl_xor(sq, 1); sq += __shfl_xor(sq, 2);
        const float mu = s * (1.f / 256.f);
        const float rstd = rsqrtf(sq * (1.f / 256.f) - mu * mu + LN_EPS);
        #pragma unroll
        for (int ii = 0; ii < 8; ++ii) {
            const float4 qa = *reinterpret_cast<const float4*>(base + ii * 8);
            const float4 qb = *reinterpret_cast<const float4*>(base + ii * 8 + 4);
            const float xs[8] = { qa.x*scale, qa.y*scale, qa.z*scale, qa.w*scale,
                                  qb.x*scale, qb.y*scale, qb.z*scale, qb.w*scale };
            uint w32[4];
            #pragma unroll
            for (int h2 = 0; h2 < 4; ++h2) {
                const int c = sub * 64 + ii * 8 + h2 * 2;
                const float x0 = (xs[h2*2 + 0] - mu) * rstd * ln2_g[c + 0] + ln2_b[c + 0];
                const float x1 = (xs[h2*2 + 1] - mu) * rstd * ln2_g[c + 1] + ln2_b[c + 1];
                w32[h2] = (uint)f2bf(x0) | ((uint)f2bf(x1) << 16);
            }
            int byte = r * 512 + sub * 128 + ii * 16;
            byte ^= ((byte >> 9) & 7) << 4;
            *reinterpret_cast<uint4*>(sAb + byte) = make_uint4(w32[0], w32[1], w32[2], w32[3]);
        }
    }
    __syncthreads();

    const int lane = t & 63;
    const int w = t >> 6;
    const int lhi = lane >> 4, llo = lane & 15;

    f32x4 acc[4][2];
    #pragma unroll
    for (int m = 0; m < 4; ++m)
        #pragma unroll
        for (int n = 0; n < 2; ++n) acc[m][n] = (f32x4){0.f, 0.f, 0.f, 0.f};

    #pragma unroll
    for (int kf = 0; kf < 8; ++kf) {
        bf16x8 a[4], b[2];
        #pragma unroll
        for (int m = 0; m < 4; ++m) {
            const int row = m * 16 + llo;
            int byte = row * 512 + kf * 64 + lhi * 16;
            byte ^= ((byte >> 9) & 7) << 4;
            a[m] = *reinterpret_cast<const bf16x8*>(sAb + byte);
        }
        #pragma unroll
        for (int nf = 0; nf < 2; ++nf) {
            const int nblk = w * 2 + nf;
            b[nf] = *reinterpret_cast<const bf16x8*>(p.W1F + ((size_t)(nblk * 8 + kf) * 64 + lane) * 8);
        }
        #pragma unroll
        for (int m = 0; m < 4; ++m)
            #pragma unroll
            for (int nf = 0; nf < 2; ++nf)
                acc[m][nf] = __builtin_amdgcn_mfma_f32_16x16x32_bf16(a[m], b[nf], acc[m][nf], 0, 0, 0);
    }

    // epilogue: bias + ELU + dot(W2) + 16-lane reduce + cross-wave reduce
    float b1v[2], w2v[2];
    #pragma unroll
    for (int nf = 0; nf < 2; ++nf) {
        const int col = w * 32 + nf * 16 + llo;
        b1v[nf] = b1[col];
        w2v[nf] = W2[col];
    }
    #pragma unroll
    for (int m = 0; m < 4; ++m) {
        #pragma unroll
        for (int j = 0; j < 4; ++j) {
            float pr = 0.f;
            #pragma unroll
            for (int nf = 0; nf < 2; ++nf) {
                float x = acc[m][nf][j] + b1v[nf];
                x = x > 0.f ? x : (__expf(x) - 1.f);
                pr += x * w2v[nf];
            }
            pr += __shfl_xor(pr, 1); pr += __shfl_xor(pr, 2);
            pr += __shfl_xor(pr, 4); pr += __shfl_xor(pr, 8);
            if (llo == 0) sPart[w][m * 16 + lhi * 4 + j] = pr;
        }
    }
    __syncthreads();
    if (t < 64) {
        const int eid = sEid[t];
        if (eid >= 0) out[eid] = sPart[0][t] + sPart[1][t] + sPart[2][t] + sPart[3][t] + b2[0];
    }
}

extern "C" void kernel_launch(void* const* d_in, const int* in_sizes, int n_in,
                              void* d_out, int out_size, void* d_ws, size_t ws_size,
                              hipStream_t stream) {
    const float* y       = (const float*)d_in[0];
    const int*   src     = (const int*)d_in[1];
    const int*   dst     = (const int*)d_in[2];
    const int*   n_nodes = (const int*)d_in[3];
    const float* ln_g    = (const float*)d_in[4];
    const float* ln_b    = (const float*)d_in[5];
    const float* Wl      = (const float*)d_in[6];
    const float* bl      = (const float*)d_in[7];
    const float* Wr      = (const float*)d_in[8];
    const float* br      = (const float*)d_in[9];
    const float* ln2_g   = (const float*)d_in[10];
    const float* ln2_b   = (const float*)d_in[11];
    const float* W1      = (const float*)d_in[12];
    const float* b1      = (const float*)d_in[13];
    const float* W2      = (const float*)d_in[14];
    const float* b2      = (const float*)d_in[15];
    float* out = (float*)d_out;
    float* ws  = (float*)d_ws;

    const int E = in_sizes[0] / 128;
    const int eb = (E + 63) / 64;

    init_kernel<<<2048, 256, 0, stream>>>(ws, n_nodes, E);
    hist_kernel<<<(E + 255) / 256, 256, 0, stream>>>(dst, ws, n_nodes, E);
    scan_kernel<<<1, 256, 0, stream>>>(ws, n_nodes, E);
    scatter_kernel<<<(E + 255) / 256, 256, 0, stream>>>(dst, ws, n_nodes, E);
    bsort_kernel<<<512, 256, 0, stream>>>(ws, n_nodes, E);
    prep_w_kernel<<<256, 256, 0, stream>>>(Wl, Wr, W1, ws, n_nodes, E);
    gates_kernel<<<eb, 256, 0, stream>>>(y, dst, ln_g, ln_b, bl, br, ws, n_nodes, E);
    mlp_kernel<<<eb, 256, 0, stream>>>(src, dst, ln2_g, ln2_b, b1, W2, b2, ws, n_nodes, out, E);
}

// Round 5
// 817.152 us; speedup vs baseline: 25.2258x; 1.1082x over previous
//
#include <hip/hip_runtime.h>
#include <hip/hip_bf16.h>

#define LN_EPS 1e-5f

typedef __attribute__((ext_vector_type(8))) short bf16x8;
typedef __attribute__((ext_vector_type(4))) float f32x4;

__device__ __forceinline__ float sigmoidf_(float x) { return 1.0f / (1.0f + __expf(-x)); }
__device__ __forceinline__ ushort f2bf(float x) {
    __hip_bfloat16 h = __float2bfloat16(x);   // RNE
    return __builtin_bit_cast(ushort, h);
}
// m204 bijective XCD-chunked swizzle (8 XCDs)
__device__ __forceinline__ int xcd_swz(int bid, int nwg) {
    const int q = nwg >> 3, r = nwg & 7;
    const int xcd = bid & 7, idx = bid >> 3;
    return (xcd < r ? xcd * (q + 1) : r * (q + 1) + (xcd - r) * q) + idx;
}

// ws layout (N read on device):
//   float aggL[N*128]; float aggR[N*128]; float rd[N];
//   int ideg[N]; int ioff[N+1]; int icur[N]; int elist[E];
//   ushort WgF[16*4*64*8]; ushort W1F[8*8*64*8]
struct WsPtrs {
    float *aggL, *aggR, *rd;
    int *ideg, *ioff, *icur, *elist;
    ushort *WgF, *W1F;
    int N;
};
__device__ __forceinline__ WsPtrs ws_ptrs(float* ws, const int* n_nodes_p, int E) {
    WsPtrs p;
    p.N    = *n_nodes_p;
    p.aggL = ws;
    p.aggR = ws + (size_t)p.N * 128;
    p.rd   = ws + (size_t)p.N * 256;
    p.ideg = (int*)(ws + (size_t)p.N * 257);
    p.ioff = p.ideg + p.N;
    p.icur = p.ioff + p.N + 1;
    p.elist = p.icur + p.N;
    p.WgF = (ushort*)(((uintptr_t)(p.elist + E) + 15) & ~(uintptr_t)15);
    p.W1F = p.WgF + 32768;
    return p;
}

// ---------------- zero agg + deg ----------------
__global__ void init_kernel(float* __restrict__ ws, const int* __restrict__ n_nodes_p, int E) {
    WsPtrs p = ws_ptrs(ws, n_nodes_p, E);
    const long long stride = (long long)gridDim.x * blockDim.x;
    const long long tid = (long long)blockIdx.x * blockDim.x + threadIdx.x;
    const long long nf = (long long)p.N * 256;
    for (long long i = tid; i < nf; i += stride) ws[i] = 0.0f;
    for (long long i = tid; i < p.N; i += stride) p.ideg[i] = 0;
}

// ---------------- histogram of dst ----------------
__global__ void hist_kernel(const int* __restrict__ dst, float* __restrict__ ws,
                            const int* __restrict__ n_nodes_p, int E) {
    WsPtrs p = ws_ptrs(ws, n_nodes_p, E);
    const int i = blockIdx.x * blockDim.x + threadIdx.x;
    if (i < E) atomicAdd(&p.ideg[dst[i]], 1);
}

// ---------------- exclusive scan (single block) + rd = 1/max(deg,1) ----------------
__global__ __launch_bounds__(256) void scan_kernel(float* __restrict__ ws,
                                                   const int* __restrict__ n_nodes_p, int E) {
    WsPtrs p = ws_ptrs(ws, n_nodes_p, E);
    __shared__ int wsum[4];
    __shared__ int carry_s;
    const int t = threadIdx.x;
    const int lane = t & 63, wid = t >> 6;
    if (t == 0) carry_s = 0;
    __syncthreads();
    for (int base = 0; base < p.N; base += 1024) {
        const int i0 = base + t * 4;
        const int v0 = (i0 + 0 < p.N) ? p.ideg[i0 + 0] : 0;
        const int v1 = (i0 + 1 < p.N) ? p.ideg[i0 + 1] : 0;
        const int v2 = (i0 + 2 < p.N) ? p.ideg[i0 + 2] : 0;
        const int v3 = (i0 + 3 < p.N) ? p.ideg[i0 + 3] : 0;
        const int s = v0 + v1 + v2 + v3;
        int sc = s;
        #pragma unroll
        for (int off = 1; off < 64; off <<= 1) {
            const int n = __shfl_up(sc, off);
            if (lane >= off) sc += n;
        }
        if (lane == 63) wsum[wid] = sc;
        __syncthreads();
        int woff = 0;
        #pragma unroll
        for (int w = 0; w < 4; ++w) if (w < wid) woff += wsum[w];
        const int carry = carry_s;
        __syncthreads();
        const int excl = carry + woff + (sc - s);
        if (i0 + 0 < p.N) { p.ioff[i0+0] = excl;          p.icur[i0+0] = excl;          p.rd[i0+0] = 1.0f / fmaxf((float)v0, 1.0f); }
        if (i0 + 1 < p.N) { p.ioff[i0+1] = excl+v0;       p.icur[i0+1] = excl+v0;       p.rd[i0+1] = 1.0f / fmaxf((float)v1, 1.0f); }
        if (i0 + 2 < p.N) { p.ioff[i0+2] = excl+v0+v1;    p.icur[i0+2] = excl+v0+v1;    p.rd[i0+2] = 1.0f / fmaxf((float)v2, 1.0f); }
        if (i0 + 3 < p.N) { p.ioff[i0+3] = excl+v0+v1+v2; p.icur[i0+3] = excl+v0+v1+v2; p.rd[i0+3] = 1.0f / fmaxf((float)v3, 1.0f); }
        if (t == 255) carry_s = carry + woff + sc;
        __syncthreads();
    }
    if (t == 0) p.ioff[p.N] = carry_s;
}

// ---------------- scatter edge ids into buckets ----------------
__global__ void scatter_kernel(const int* __restrict__ dst, float* __restrict__ ws,
                               const int* __restrict__ n_nodes_p, int E) {
    WsPtrs p = ws_ptrs(ws, n_nodes_p, E);
    const int i = blockIdx.x * blockDim.x + threadIdx.x;
    if (i < E) {
        const int pos = atomicAdd(&p.icur[dst[i]], 1);
        p.elist[pos] = i;
    }
}

// ---------------- per-bucket insertion sort (deterministic order) ----------------
__global__ void bsort_kernel(float* __restrict__ ws, const int* __restrict__ n_nodes_p, int E) {
    WsPtrs p = ws_ptrs(ws, n_nodes_p, E);
    const int stride = gridDim.x * blockDim.x;
    for (int i = blockIdx.x * blockDim.x + threadIdx.x; i < p.N; i += stride) {
        const int beg = p.ioff[i], end = p.ioff[i + 1];
        for (int a = beg + 1; a < end; ++a) {
            const int key = p.elist[a];
            int b = a - 1;
            while (b >= beg && p.elist[b] > key) { p.elist[b + 1] = p.elist[b]; --b; }
            p.elist[b + 1] = key;
        }
    }
}

// ---------------- build fragment-major bf16 B tables ----------------
__global__ void prep_w_kernel(const float* __restrict__ Wl, const float* __restrict__ Wr,
                              const float* __restrict__ W1,
                              float* __restrict__ ws, const int* __restrict__ n_nodes_p, int E) {
    WsPtrs p = ws_ptrs(ws, n_nodes_p, E);
    const int i = blockIdx.x * blockDim.x + threadIdx.x;
    if (i < 32768) {
        const int i8 = i & 7, lane = (i >> 3) & 63, kf = (i >> 9) & 3, nblk = i >> 11;
        const int k = kf * 32 + (lane >> 4) * 8 + i8;
        const int n = nblk * 16 + (lane & 15);
        const float val = (n < 128) ? Wl[k * 128 + n] : Wr[k * 128 + (n - 128)];
        p.WgF[i] = f2bf(val);
    } else if (i < 65536) {
        const int j = i - 32768;
        const int i8 = j & 7, lane = (j >> 3) & 63, kf = (j >> 9) & 7, nblk = j >> 12;
        const int k = kf * 32 + (lane >> 4) * 8 + i8;
        const int n = nblk * 16 + (lane & 15);
        p.W1F[j] = f2bf(W1[k * 128 + n]);
    }
}

// ---------------- gates: LN + MFMA dual-gate GEMM + sigmoid + compressed scatter ----------------
// 512 threads (8 waves), 128 dst-sorted edges/block.
// Wave w: rowh = w>>2 (rows rowh*64..+64), colw = w&3 (outcols colw*64..+64 over [Wl|Wr]).
// sA: [128 rows][128 cols] bf16, byte = row*256 + col*2, XOR-swizzle ((byte>>8)&7)<<4.
__global__ __launch_bounds__(512) void gates_kernel(
    const float* __restrict__ y, const int* __restrict__ dst,
    const float* __restrict__ ln_g, const float* __restrict__ ln_b,
    const float* __restrict__ bl, const float* __restrict__ br,
    float* __restrict__ ws, const int* __restrict__ n_nodes_p, int E)
{
    __shared__ ushort sA[128 * 128];   // 32 KB
    __shared__ int sNode[128];

    WsPtrs p = ws_ptrs(ws, n_nodes_p, E);
    char* sAb = reinterpret_cast<char*>(sA);
    const int t = threadIdx.x;
    const int bid = xcd_swz(blockIdx.x, gridDim.x);
    const int s0 = bid * 128;

    if (t < 128) {
        const int j = s0 + t;
        const int eid = (j < E) ? p.elist[j] : -1;
        sNode[t] = (eid >= 0) ? dst[eid] : -1;
    }

    // LayerNorm -> sA. 4 threads/row, sub owns cols [32*sub, 32*sub+32).
    {
        const int r = t >> 2, sub = t & 3;
        const int je = s0 + r;
        const int eid = (je < E) ? p.elist[je] : 0;
        const float* yr = y + (size_t)eid * 128;
        float v[32];
        float s = 0.f, sq = 0.f;
        #pragma unroll
        for (int i = 0; i < 8; ++i) {
            const float4 q = *reinterpret_cast<const float4*>(yr + sub * 32 + i * 4);
            v[i*4+0] = q.x; v[i*4+1] = q.y; v[i*4+2] = q.z; v[i*4+3] = q.w;
            s  += q.x + q.y + q.z + q.w;
            sq += q.x*q.x + q.y*q.y + q.z*q.z + q.w*q.w;
        }
        s  += __shfl_xor(s, 1);  s  += __shfl_xor(s, 2);
        sq += __shfl_xor(sq, 1); sq += __shfl_xor(sq, 2);
        const float mu = s * (1.f / 128.f);
        const float rstd = rsqrtf(sq * (1.f / 128.f) - mu * mu + LN_EPS);
        #pragma unroll
        for (int i = 0; i < 4; ++i) {
            uint w32[4];
            #pragma unroll
            for (int h2 = 0; h2 < 4; ++h2) {
                const int c = sub * 32 + i * 8 + h2 * 2;
                const float x0 = (v[i*8 + h2*2 + 0] - mu) * rstd * ln_g[c + 0] + ln_b[c + 0];
                const float x1 = (v[i*8 + h2*2 + 1] - mu) * rstd * ln_g[c + 1] + ln_b[c + 1];
                w32[h2] = (uint)f2bf(x0) | ((uint)f2bf(x1) << 16);
            }
            int byte = r * 256 + sub * 64 + i * 16;
            byte ^= ((byte >> 8) & 7) << 4;
            *reinterpret_cast<uint4*>(sAb + byte) = make_uint4(w32[0], w32[1], w32[2], w32[3]);
        }
    }
    __syncthreads();

    const int lane = t & 63;
    const int w8 = t >> 6;
    const int rowh = w8 >> 2, colw = w8 & 3;
    const int lhi = lane >> 4, llo = lane & 15;

    f32x4 acc[4][4];
    #pragma unroll
    for (int m = 0; m < 4; ++m)
        #pragma unroll
        for (int n = 0; n < 4; ++n) acc[m][n] = (f32x4){0.f, 0.f, 0.f, 0.f};

    #pragma unroll
    for (int kf = 0; kf < 4; ++kf) {
        bf16x8 a[4], b[4];
        #pragma unroll
        for (int m = 0; m < 4; ++m) {
            const int row = rowh * 64 + m * 16 + llo;
            int byte = row * 256 + kf * 64 + lhi * 16;
            byte ^= ((byte >> 8) & 7) << 4;
            a[m] = *reinterpret_cast<const bf16x8*>(sAb + byte);
        }
        #pragma unroll
        for (int nf = 0; nf < 4; ++nf) {
            const int nblk = colw * 4 + nf;
            b[nf] = *reinterpret_cast<const bf16x8*>(p.WgF + ((size_t)(nblk * 4 + kf) * 64 + lane) * 8);
        }
        #pragma unroll
        for (int m = 0; m < 4; ++m)
            #pragma unroll
            for (int nf = 0; nf < 4; ++nf)
                acc[m][nf] = __builtin_amdgcn_mfma_f32_16x16x32_bf16(a[m], b[nf], acc[m][nf], 0, 0, 0);
    }

    // epilogue: sigmoid + run-compressed atomics. D: col=lane&15, row=(lane>>4)*4+j.
    const int g = colw >> 1;
    float* ag = g ? p.aggR : p.aggL;
    const float* bp = g ? br : bl;
    #pragma unroll
    for (int nf = 0; nf < 4; ++nf) {
        const int col = colw * 64 + nf * 16 + llo;
        const int lcol = col & 127;
        const float bias = bp[lcol];
        float runv = 0.f;
        int rnode = -1;
        #pragma unroll
        for (int m = 0; m < 4; ++m) {
            #pragma unroll
            for (int j = 0; j < 4; ++j) {
                const int el = rowh * 64 + m * 16 + lhi * 4 + j;
                const int node = sNode[el];
                const float val = sigmoidf_(acc[m][nf][j] + bias);
                if (node != rnode) {
                    if (rnode >= 0) atomicAdd(ag + (size_t)rnode * 128 + lcol, runv);
                    rnode = node;
                    runv = val;
                } else {
                    runv += val;
                }
            }
        }
        if (rnode >= 0) atomicAdd(ag + (size_t)rnode * 128 + lcol, runv);
    }
}

// ---------------- mlp: gather + LN(256) + MFMA GEMM + ELU + W2 dot ----------------
// 512 threads (8 waves), 128 dst-sorted edges/block.
// Wave w: rowh = w>>2 (rows rowh*64..+64), colw = w&3 (outcols colw*32..+32).
// sA: [128 rows][256 cols] bf16, byte = row*512 + col*2, XOR-swizzle ((byte>>9)&7)<<4.
__global__ __launch_bounds__(512) void mlp_kernel(
    const int* __restrict__ src, const int* __restrict__ dst,
    const float* __restrict__ ln2_g, const float* __restrict__ ln2_b,
    const float* __restrict__ b1, const float* __restrict__ W2,
    const float* __restrict__ b2,
    float* __restrict__ ws, const int* __restrict__ n_nodes_p,
    float* __restrict__ out, int E)
{
    __shared__ ushort sA[128 * 256];   // 64 KB
    __shared__ float sPart[4][128];
    __shared__ int sEid[128];

    WsPtrs p = ws_ptrs(ws, n_nodes_p, E);
    char* sAb = reinterpret_cast<char*>(sA);
    const int t = threadIdx.x;
    const int bid = xcd_swz(blockIdx.x, gridDim.x);
    const int s0 = bid * 128;

    if (t < 128) {
        const int j = s0 + t;
        sEid[t] = (j < E) ? p.elist[j] : -1;
    }

    // gather + LN(256) -> sA. 4 threads/row, sub owns cols [64*sub, 64*sub+64).
    {
        const int r = t >> 2, sub = t & 3;
        const int je = s0 + r;
        const int eid = (je < E) ? p.elist[je] : -1;
        const bool vld = eid >= 0;
        const int node = vld ? ((sub < 2) ? src[eid] : dst[eid]) : 0;
        const float* base = ((sub < 2) ? p.aggL : p.aggR) + (size_t)node * 128 + (sub & 1) * 64;
        const float scale = vld ? p.rd[node] : 0.f;
        float s = 0.f, sq = 0.f;
        #pragma unroll
        for (int i = 0; i < 16; ++i) {
            const float4 q = *reinterpret_cast<const float4*>(base + i * 4);
            const float x0 = q.x * scale, x1 = q.y * scale, x2 = q.z * scale, x3 = q.w * scale;
            s  += x0 + x1 + x2 + x3;
            sq += x0*x0 + x1*x1 + x2*x2 + x3*x3;
        }
        s  += __shfl_xor(s, 1);  s  += __shfl_xor(s, 2);
        sq += __shfl_xor(sq, 1); sq += __shfl_xor(sq, 2);
        const float mu = s * (1.f / 256.f);
        const float rstd = rsqrtf(sq * (1.f / 256.f) - mu * mu + LN_EPS);
        #pragma unroll
        for (int ii = 0; ii < 8; ++ii) {
            const float4 qa = *reinterpret_cast<const float4*>(base + ii * 8);
            const float4 qb = *reinterpret_cast<const float4*>(base + ii * 8 + 4);
            const float xs[8] = { qa.x*scale, qa.y*scale, qa.z*scale, qa.w*scale,
                                  qb.x*scale, qb.y*scale, qb.z*scale, qb.w*scale };
            uint w32[4];
            #pragma unroll
            for (int h2 = 0; h2 < 4; ++h2) {
                const int c = sub * 64 + ii * 8 + h2 * 2;
                const float x0 = (xs[h2*2 + 0] - mu) * rstd * ln2_g[c + 0] + ln2_b[c + 0];
                const float x1 = (xs[h2*2 + 1] - mu) * rstd * ln2_g[c + 1] + ln2_b[c + 1];
                w32[h2] = (uint)f2bf(x0) | ((uint)f2bf(x1) << 16);
            }
            int byte = r * 512 + sub * 128 + ii * 16;
            byte ^= ((byte >> 9) & 7) << 4;
            *reinterpret_cast<uint4*>(sAb + byte) = make_uint4(w32[0], w32[1], w32[2], w32[3]);
        }
    }
    __syncthreads();

    const int lane = t & 63;
    const int w8 = t >> 6;
    const int rowh = w8 >> 2, colw = w8 & 3;
    const int lhi = lane >> 4, llo = lane & 15;

    f32x4 acc[4][2];
    #pragma unroll
    for (int m = 0; m < 4; ++m)
        #pragma unroll
        for (int n = 0; n < 2; ++n) acc[m][n] = (f32x4){0.f, 0.f, 0.f, 0.f};

    #pragma unroll
    for (int kf = 0; kf < 8; ++kf) {
        bf16x8 a[4], b[2];
        #pragma unroll
        for (int m = 0; m < 4; ++m) {
            const int row = rowh * 64 + m * 16 + llo;
            int byte = row * 512 + kf * 64 + lhi * 16;
            byte ^= ((byte >> 9) & 7) << 4;
            a[m] = *reinterpret_cast<const bf16x8*>(sAb + byte);
        }
        #pragma unroll
        for (int nf = 0; nf < 2; ++nf) {
            const int nblk = colw * 2 + nf;
            b[nf] = *reinterpret_cast<const bf16x8*>(p.W1F + ((size_t)(nblk * 8 + kf) * 64 + lane) * 8);
        }
        #pragma unroll
        for (int m = 0; m < 4; ++m)
            #pragma unroll
            for (int nf = 0; nf < 2; ++nf)
                acc[m][nf] = __builtin_amdgcn_mfma_f32_16x16x32_bf16(a[m], b[nf], acc[m][nf], 0, 0, 0);
    }

    // epilogue: bias + ELU + dot(W2) + 16-lane reduce + cross-wave reduce
    float b1v[2], w2v[2];
    #pragma unroll
    for (int nf = 0; nf < 2; ++nf) {
        const int col = colw * 32 + nf * 16 + llo;
        b1v[nf] = b1[col];
        w2v[nf] = W2[col];
    }
    #pragma unroll
    for (int m = 0; m < 4; ++m) {
        #pragma unroll
        for (int j = 0; j < 4; ++j) {
            float pr = 0.f;
            #pragma unroll
            for (int nf = 0; nf < 2; ++nf) {
                float x = acc[m][nf][j] + b1v[nf];
                x = x > 0.f ? x : (__expf(x) - 1.f);
                pr += x * w2v[nf];
            }
            pr += __shfl_xor(pr, 1); pr += __shfl_xor(pr, 2);
            pr += __shfl_xor(pr, 4); pr += __shfl_xor(pr, 8);
            if (llo == 0) sPart[colw][rowh * 64 + m * 16 + lhi * 4 + j] = pr;
        }
    }
    __syncthreads();
    if (t < 128) {
        const int eid = sEid[t];
        if (eid >= 0) out[eid] = sPart[0][t] + sPart[1][t] + sPart[2][t] + sPart[3][t] + b2[0];
    }
}

extern "C" void kernel_launch(void* const* d_in, const int* in_sizes, int n_in,
                              void* d_out, int out_size, void* d_ws, size_t ws_size,
                              hipStream_t stream) {
    const float* y       = (const float*)d_in[0];
    const int*   src     = (const int*)d_in[1];
    const int*   dst     = (const int*)d_in[2];
    const int*   n_nodes = (const int*)d_in[3];
    const float* ln_g    = (const float*)d_in[4];
    const float* ln_b    = (const float*)d_in[5];
    const float* Wl      = (const float*)d_in[6];
    const float* bl      = (const float*)d_in[7];
    const float* Wr      = (const float*)d_in[8];
    const float* br      = (const float*)d_in[9];
    const float* ln2_g   = (const float*)d_in[10];
    const float* ln2_b   = (const float*)d_in[11];
    const float* W1      = (const float*)d_in[12];
    const float* b1      = (const float*)d_in[13];
    const float* W2      = (const float*)d_in[14];
    const float* b2      = (const float*)d_in[15];
    float* out = (float*)d_out;
    float* ws  = (float*)d_ws;

    const int E = in_sizes[0] / 128;
    const int eb = (E + 127) / 128;

    init_kernel<<<2048, 256, 0, stream>>>(ws, n_nodes, E);
    hist_kernel<<<(E + 255) / 256, 256, 0, stream>>>(dst, ws, n_nodes, E);
    scan_kernel<<<1, 256, 0, stream>>>(ws, n_nodes, E);
    scatter_kernel<<<(E + 255) / 256, 256, 0, stream>>>(dst, ws, n_nodes, E);
    bsort_kernel<<<512, 256, 0, stream>>>(ws, n_nodes, E);
    prep_w_kernel<<<256, 256, 0, stream>>>(Wl, Wr, W1, ws, n_nodes, E);
    gates_kernel<<<eb, 512, 0, stream>>>(y, dst, ln_g, ln_b, bl, br, ws, n_nodes, E);
    mlp_kernel<<<eb, 512, 0, stream>>>(src, dst, ln2_g, ln2_b, b1, W2, b2, ws, n_nodes, out, E);
}